// Round 5
// baseline (1405.246 us; speedup 1.0000x reference)
//
#include <hip/hip_runtime.h>
#include <hip/hip_bf16.h>
#include <hip/hip_fp16.h>

// ---- problem constants ----
#define TOK 8192      // 4*2048 tokens
#define HD 2048       // hidden
#define ID 4096       // intermediate
#define NE 8          // experts
#define NPAIR (TOK*2) // token-expert pairs (TOPK=2)
#define BM 256
#define MAXMT (NPAIR/BM + NE)   // 72 worst-case M-tiles
#define PPAD (NPAIR + NE*BM)    // 18432 worst-case padded rows

typedef unsigned short u16;
typedef unsigned int u32;
typedef __attribute__((ext_vector_type(4))) float f32x4;
typedef __attribute__((ext_vector_type(4))) int   i32x4;
typedef u16 u16x8 __attribute__((ext_vector_type(8)));
typedef u16 u16x4 __attribute__((ext_vector_type(4)));

__device__ __forceinline__ u16 f2h(float f) {
    __half h = __float2half_rn(f);
    return *reinterpret_cast<u16*>(&h);
}

// ---------------- cast x fp32 -> fp16 ----------------
__global__ void cast_x_kernel(const float* __restrict__ x, u16* __restrict__ xh) {
    size_t idx = (size_t)blockIdx.x * 256 + threadIdx.x;   // 8 elems each
    const f32x4* p = (const f32x4*)x + idx * 2;
    f32x4 a = p[0], b = p[1];
    u16x8 o;
#pragma unroll
    for (int i = 0; i < 4; ++i) { o[i] = f2h(a[i]); o[4 + i] = f2h(b[i]); }
    *((u16x8*)xh + idx) = o;
}

// ---------------- prep: w1/w3 fp32 [H][I] -> interleaved fp16 wcat [2*I][H] ----------------
__global__ __launch_bounds__(256) void prep_w13_kernel(const float* __restrict__ w1,
                                                       const float* __restrict__ w3,
                                                       u16* __restrict__ wcat) {
    __shared__ u16 tile[64][68];   // [n_local][k_local]
    const int k0 = blockIdx.x * 64, n0 = blockIdx.y * 64;
    const int e = blockIdx.z >> 1, which = blockIdx.z & 1;
    const float* src = (which ? w3 : w1) + (size_t)e * HD * ID;
    u16* dst = wcat + (size_t)e * 2 * ID * HD;
    const int tid = threadIdx.x, r = tid >> 4, c4 = (tid & 15) * 4;
#pragma unroll
    for (int i = 0; i < 4; ++i) {
        int k = k0 + r + 16 * i;
        f32x4 v = *(const f32x4*)(src + (size_t)k * ID + n0 + c4);
#pragma unroll
        for (int j = 0; j < 4; ++j) tile[c4 + j][r + 16 * i] = f2h(v[j]);
    }
    __syncthreads();
#pragma unroll
    for (int i = 0; i < 4; ++i) {
        int nl = r + 16 * i;
        int n = n0 + nl;
        int wr = ((n >> 4) << 5) | (which << 4) | (n & 15);
        u16x4 o;
#pragma unroll
        for (int j = 0; j < 4; ++j) o[j] = tile[nl][c4 + j];
        *(u16x4*)(dst + (size_t)wr * HD + k0 + c4) = o;
    }
}

// ---------------- prep: w2 fp32 [I][H] -> fp16 w2t [H][I] ----------------
__global__ __launch_bounds__(256) void prep_w2_kernel(const float* __restrict__ w2,
                                                      u16* __restrict__ w2t) {
    __shared__ u16 tile[64][68];
    const int k0 = blockIdx.x * 64, n0 = blockIdx.y * 64;
    const int e = blockIdx.z;
    const float* src = w2 + (size_t)e * ID * HD;
    u16* dst = w2t + (size_t)e * ID * HD;
    const int tid = threadIdx.x, r = tid >> 4, c4 = (tid & 15) * 4;
#pragma unroll
    for (int i = 0; i < 4; ++i) {
        int k = k0 + r + 16 * i;
        f32x4 v = *(const f32x4*)(src + (size_t)k * HD + n0 + c4);
#pragma unroll
        for (int j = 0; j < 4; ++j) tile[c4 + j][r + 16 * i] = f2h(v[j]);
    }
    __syncthreads();
#pragma unroll
    for (int i = 0; i < 4; ++i) {
        int nl = r + 16 * i;
        u16x4 o;
#pragma unroll
        for (int j = 0; j < 4; ++j) o[j] = tile[nl][c4 + j];
        *(u16x4*)(dst + (size_t)(n0 + nl) * ID + k0 + c4) = o;
    }
}

// ---------------- router: fp32 logits, softcap, softmax, top2 ----------------
__global__ void router_kernel(const float* __restrict__ x, const float* __restrict__ wg,
                              int* __restrict__ top_e, float* __restrict__ top_w,
                              int* __restrict__ counts) {
    int t = blockIdx.x * 4 + (threadIdx.x >> 6);
    int l = threadIdx.x & 63;
    const float* xr = x + (size_t)t * HD;
    float acc[NE];
#pragma unroll
    for (int e = 0; e < NE; ++e) acc[e] = 0.f;
    for (int h0 = 0; h0 < HD; h0 += 64) {
        int h = h0 + l;
        float xv = xr[h];
        const f32x4* wr = (const f32x4*)(wg + (size_t)h * NE);
        f32x4 w0 = wr[0], w1v = wr[1];
#pragma unroll
        for (int i = 0; i < 4; ++i) { acc[i] += xv * w0[i]; acc[4 + i] += xv * w1v[i]; }
    }
#pragma unroll
    for (int e = 0; e < NE; ++e) {
        float v = acc[e];
        for (int s = 32; s >= 1; s >>= 1) v += __shfl_xor(v, s);
        acc[e] = v;
    }
    if (l == 0) {
        float li[NE], mx = -1e30f;
#pragma unroll
        for (int e = 0; e < NE; ++e) { li[e] = 30.f * tanhf(acc[e] * (1.f / 30.f)); mx = fmaxf(mx, li[e]); }
        float p[NE], se = 0.f;
#pragma unroll
        for (int e = 0; e < NE; ++e) { p[e] = expf(li[e] - mx); se += p[e]; }
        float inv = 1.f / se;
        int i1 = 0; float p1 = p[0];
#pragma unroll
        for (int e = 1; e < NE; ++e) if (p[e] > p1) { p1 = p[e]; i1 = e; }
        int i2 = -1; float p2 = -1e30f;
#pragma unroll
        for (int e = 0; e < NE; ++e) if (e != i1 && p[e] > p2) { p2 = p[e]; i2 = e; }
        top_e[t * 2] = i1; top_e[t * 2 + 1] = i2;
        top_w[t * 2] = p1 * inv; top_w[t * 2 + 1] = p2 * inv;
        atomicAdd(&counts[i1], 1); atomicAdd(&counts[i2], 1);
    }
}

// ---------------- offsets + M-tile table (1 thread), 256-row tiles ----------------
__global__ void offsets_kernel(const int* __restrict__ counts, int* __restrict__ offs,
                               int* __restrict__ mt_e, int* __restrict__ mt_r0,
                               int* __restrict__ nmt) {
    if (threadIdx.x != 0) return;
    int off = 0, n = 0;
    for (int e = 0; e < NE; ++e) {
        offs[e] = off;
        int c = counts[e];
        int nt = (c + 255) >> 8;
        for (int j = 0; j < nt; ++j) { mt_e[n] = e; mt_r0[n] = off + j * 256; ++n; }
        off += nt * 256;
    }
    offs[NE] = off;
    *nmt = n;
}

// ---------------- deterministic per-expert compaction ----------------
// pair_tok2[pos] = token*2 + slot; pads = -2
__global__ void scatter_kernel(const int* __restrict__ top_e, const float* __restrict__ top_w,
                               const int* __restrict__ counts, const int* __restrict__ offs,
                               int* __restrict__ pair_tok2, float* __restrict__ pair_w) {
    const int e = blockIdx.x;
    const int tid = threadIdx.x;
    __shared__ int sc[256];
    int base = offs[e];
    for (int start = 0; start < TOK; start += 256) {
        int tk = start + tid;
        int m = 0; float w = 0.f; int slot = 0;
        int e0 = top_e[tk * 2], e1 = top_e[tk * 2 + 1];
        if (e0 == e) { m = 1; w = top_w[tk * 2]; slot = 0; }
        else if (e1 == e) { m = 1; w = top_w[tk * 2 + 1]; slot = 1; }
        sc[tid] = m;
        __syncthreads();
        for (int s = 1; s < 256; s <<= 1) {
            int v = (tid >= s) ? sc[tid - s] : 0;
            __syncthreads();
            sc[tid] += v;
            __syncthreads();
        }
        if (m) { int pos = base + sc[tid] - 1; pair_tok2[pos] = tk * 2 + slot; pair_w[pos] = w; }
        base += sc[255];
        __syncthreads();
    }
    int cnt = counts[e];
    int padded = (cnt + 255) & ~255;
    for (int r = cnt + tid; r < padded; r += 256) {
        pair_tok2[offs[e] + r] = -2;
        pair_w[offs[e] + r] = 0.f;
    }
}

// ======================= 8-phase 256x256 GEMM machinery =======================
// LDS element-bases (u16 units): A0, A1, B0, B1 each [256][64] fp16 = 16384 elems
#define A0E 0
#define A1E 16384
#define B0E 32768
#define B1E 49152

#define STAGE_A(DSTE, H) do { \
    _Pragma("unroll") \
    for (int cc_ = 0; cc_ < 2; ++cc_) { \
        __builtin_amdgcn_global_load_lds( \
            (const __attribute__((address_space(1))) void*)(abase + aoff[(H) * 2 + cc_]), \
            (__attribute__((address_space(3))) void*)(lds + (DSTE) + (H) * 8192 + cc_ * 4096 + wv * 512), \
            16, 0, 0); \
        aoff[(H) * 2 + cc_] += 128; \
    } \
} while (0)

#define STAGE_B(DSTE, H) do { \
    _Pragma("unroll") \
    for (int cc_ = 0; cc_ < 2; ++cc_) { \
        __builtin_amdgcn_global_load_lds( \
            (const __attribute__((address_space(1))) void*)(bbase + boff[(H) * 2 + cc_]), \
            (__attribute__((address_space(3))) void*)(lds + (DSTE) + (H) * 8192 + cc_ * 4096 + wv * 512), \
            16, 0, 0); \
        boff[(H) * 2 + cc_] += 128; \
    } \
} while (0)

#define LOAD_B(BUFE) do { \
    _Pragma("unroll") \
    for (int nf_ = 0; nf_ < 4; ++nf_) { \
        _Pragma("unroll") \
        for (int kk_ = 0; kk_ < 2; ++kk_) { \
            int nn_ = wn * 64 + nf_ * 16 + l15; \
            int lb_ = (lh * 16 + kk_ * 64) ^ ((nn_ & 7) << 4); \
            bb[nf_][kk_] = *(const i32x4*)((const char*)lds + (BUFE) * 2 + nn_ * 128 + lb_); \
        } } \
} while (0)

// phase: {ds_read a-frags | stage | barrier | lgkm0+schedbar | prio1 | 16 MFMA | prio0 | tail | barrier}
#define DO_PHASE(Q, ABUF, STAGE_STMT, TAIL_STMT) do { \
    i32x4 aa_[2][2]; \
    _Pragma("unroll") \
    for (int m2_ = 0; m2_ < 2; ++m2_) { \
        _Pragma("unroll") \
        for (int kk_ = 0; kk_ < 2; ++kk_) { \
            int rr_ = wm * 128 + ((Q) * 2 + m2_) * 16 + l15; \
            int lb_ = (lh * 16 + kk_ * 64) ^ ((rr_ & 7) << 4); \
            aa_[m2_][kk_] = *(const i32x4*)((const char*)lds + (ABUF) * 2 + rr_ * 128 + lb_); \
        } } \
    STAGE_STMT; \
    __builtin_amdgcn_s_barrier(); \
    asm volatile("s_waitcnt lgkmcnt(0)" ::: "memory"); \
    __builtin_amdgcn_sched_barrier(0); \
    __builtin_amdgcn_s_setprio(1); \
    _Pragma("unroll") \
    for (int m2_ = 0; m2_ < 2; ++m2_) { \
        _Pragma("unroll") \
        for (int nf_ = 0; nf_ < 4; ++nf_) { \
            _Pragma("unroll") \
            for (int kk_ = 0; kk_ < 2; ++kk_) { \
                asm("v_mfma_f32_16x16x32_f16 %0, %1, %2, %0" \
                    : "+v"(acc[(Q) * 2 + m2_][nf_]) \
                    : "v"(aa_[m2_][kk_]), "v"(bb[nf_][kk_])); \
            } } } \
    __builtin_amdgcn_s_setprio(0); \
    TAIL_STMT; \
    __builtin_amdgcn_s_barrier(); \
} while (0)

#define VM4 asm volatile("s_waitcnt vmcnt(4)" ::: "memory")
#define VM0 asm volatile("s_waitcnt vmcnt(0)" ::: "memory")

// ---------------- GEMM1: h = silu(x@w1)*(x@w3), 256x256 8-phase fp16 MFMA ----------------
__global__ __launch_bounds__(512, 2) void gemm1_kernel(
    const u16* __restrict__ xh, const u16* __restrict__ wcat,
    const int* __restrict__ pair_tok2, const int* __restrict__ mt_e,
    const int* __restrict__ mt_r0, const int* __restrict__ nmt,
    u16* __restrict__ hb) {
    // XCD-pure 32-block clusters (4mt x 8by); grid 2304 = 72 clusters
    int p = blockIdx.x;
    int xc = p & 7, jj_ = p >> 3, cl = jj_ >> 5, sl = jj_ & 31;
    int C = cl * 8 + xc;
    int mt = (C % 18) * 4 + (sl >> 3);
    int by = (C / 18) * 8 + (sl & 7);
    if (mt >= *nmt) return;
    const int e = mt_e[mt], row0 = mt_r0[mt];
    const int tid = threadIdx.x, lane = tid & 63, wv = tid >> 6;
    const int wm = wv >> 2, wn = wv & 3;
    const int l15 = lane & 15, lh = lane >> 4;

    __shared__ u16 lds[65536];   // 128 KB

    u32 aoff[4], boff[4];
    const char* abase = (const char*)xh;
    const char* bbase = (const char*)(wcat + (size_t)e * 2 * ID * HD);
    {
        int rl_ = tid >> 3, ch_ = tid & 7;
#pragma unroll
        for (int h = 0; h < 2; ++h)
#pragma unroll
            for (int cc = 0; cc < 2; ++cc) {
                int r = h * 128 + cc * 64 + rl_;
                int kbs = (ch_ * 16) ^ ((r & 7) << 4);
                int pt2 = pair_tok2[row0 + r];
                int tok = pt2 < 0 ? 0 : (pt2 >> 1);
                aoff[h * 2 + cc] = (u32)(tok * (HD * 2)) + kbs;
                boff[h * 2 + cc] = (u32)((by * 256 + r) * (HD * 2)) + kbs;
            }
    }

    f32x4 acc[8][4];
#pragma unroll
    for (int i0 = 0; i0 < 8; ++i0)
#pragma unroll
        for (int i1 = 0; i1 < 4; ++i1) acc[i0][i1] = (f32x4)0.f;
    i32x4 bb[4][2];

    // prologue: A(0), B(0), B(1); allow B(1) in flight
    STAGE_A(A0E, 0); STAGE_A(A0E, 1);
    STAGE_B(B0E, 0); STAGE_B(B0E, 1);
    STAGE_B(B1E, 0); STAGE_B(B1E, 1);
    VM4;
    __builtin_amdgcn_s_barrier();

    const int NT = HD / 64;   // 32 (even)
#pragma unroll 1
    for (int g2 = 0; g2 < NT; g2 += 2) {
        const bool nt_ = (g2 + 2 < NT);
        // even group: A=A0, B=B0; stage A(g2+1)->A1, B(g2+2)->B0
        LOAD_B(B0E);
        DO_PHASE(0, A0E, STAGE_A(A1E, 0), {});
        DO_PHASE(1, A0E, STAGE_A(A1E, 1), {});
        DO_PHASE(2, A0E, if (nt_) STAGE_B(B0E, 0), {});
        DO_PHASE(3, A0E, if (nt_) STAGE_B(B0E, 1),
                 if (nt_) { VM4; } else { VM0; });
        // odd group: A=A1, B=B1; stage A(g2+2)->A0, B(g2+3)->B1
        LOAD_B(B1E);
        DO_PHASE(0, A1E, if (nt_) STAGE_A(A0E, 0), {});
        DO_PHASE(1, A1E, if (nt_) STAGE_A(A0E, 1), {});
        DO_PHASE(2, A1E, if (nt_) STAGE_B(B1E, 0), {});
        DO_PHASE(3, A1E, if (nt_) STAGE_B(B1E, 1),
                 if (nt_) { VM4; } else { VM0; });
    }

    // epilogue: nf even = gate, nf odd = up; real col = by*128 + wn*32 + np*16 + l15
#pragma unroll
    for (int mf = 0; mf < 8; ++mf) {
#pragma unroll
        for (int j = 0; j < 4; ++j) {
            size_t rr = (size_t)row0 + wm * 128 + mf * 16 + lh * 4 + j;
            u16* hp_ = hb + rr * ID + by * 128 + wn * 32 + l15;
#pragma unroll
            for (int np = 0; np < 2; ++np) {
                float g = acc[mf][2 * np][j], u = acc[mf][2 * np + 1][j];
                float s = g / (1.f + expf(-g));
                hp_[np * 16] = f2h(s * u);
            }
        }
    }
}

// ---------------- GEMM2: ob[tok*2+slot] = (h@w2t)*weight, 256x256 8-phase ----------------
__global__ __launch_bounds__(512, 2) void gemm2_kernel(
    const u16* __restrict__ hb, const u16* __restrict__ w2t,
    const int* __restrict__ pair_tok2, const float* __restrict__ pair_w,
    const int* __restrict__ mt_e, const int* __restrict__ mt_r0, const int* __restrict__ nmt,
    float* __restrict__ ob) {
    // XCD-pure 32-block clusters (4mt x 8by); grid 768 = 24 clusters, mt padded to 96
    int p = blockIdx.x;
    int xc = p & 7, jj_ = p >> 3, cl = jj_ >> 5, sl = jj_ & 31;
    int C = cl * 8 + xc;
    int mt = C * 4 + (sl >> 3);
    int by = sl & 7;
    if (mt >= *nmt) return;
    const int e = mt_e[mt], row0 = mt_r0[mt];
    const int tid = threadIdx.x, lane = tid & 63, wv = tid >> 6;
    const int wm = wv >> 2, wn = wv & 3;
    const int l15 = lane & 15, lh = lane >> 4;

    __shared__ u16 lds[65536];

    u32 aoff[4], boff[4];
    const char* abase = (const char*)hb;
    const char* bbase = (const char*)(w2t + (size_t)e * HD * ID);
    {
        int rl_ = tid >> 3, ch_ = tid & 7;
#pragma unroll
        for (int h = 0; h < 2; ++h)
#pragma unroll
            for (int cc = 0; cc < 2; ++cc) {
                int r = h * 128 + cc * 64 + rl_;
                int kbs = (ch_ * 16) ^ ((r & 7) << 4);
                aoff[h * 2 + cc] = (u32)((row0 + r) * (ID * 2)) + kbs;
                boff[h * 2 + cc] = (u32)((by * 256 + r) * (ID * 2)) + kbs;
            }
    }

    f32x4 acc[8][4];
#pragma unroll
    for (int i0 = 0; i0 < 8; ++i0)
#pragma unroll
        for (int i1 = 0; i1 < 4; ++i1) acc[i0][i1] = (f32x4)0.f;
    i32x4 bb[4][2];

    STAGE_A(A0E, 0); STAGE_A(A0E, 1);
    STAGE_B(B0E, 0); STAGE_B(B0E, 1);
    STAGE_B(B1E, 0); STAGE_B(B1E, 1);
    VM4;
    __builtin_amdgcn_s_barrier();

    const int NT = ID / 64;   // 64 (even)
#pragma unroll 1
    for (int g2 = 0; g2 < NT; g2 += 2) {
        const bool nt_ = (g2 + 2 < NT);
        LOAD_B(B0E);
        DO_PHASE(0, A0E, STAGE_A(A1E, 0), {});
        DO_PHASE(1, A0E, STAGE_A(A1E, 1), {});
        DO_PHASE(2, A0E, if (nt_) STAGE_B(B0E, 0), {});
        DO_PHASE(3, A0E, if (nt_) STAGE_B(B0E, 1),
                 if (nt_) { VM4; } else { VM0; });
        LOAD_B(B1E);
        DO_PHASE(0, A1E, if (nt_) STAGE_A(A0E, 0), {});
        DO_PHASE(1, A1E, if (nt_) STAGE_A(A0E, 1), {});
        DO_PHASE(2, A1E, if (nt_) STAGE_B(B1E, 0), {});
        DO_PHASE(3, A1E, if (nt_) STAGE_B(B1E, 1),
                 if (nt_) { VM4; } else { VM0; });
    }

#pragma unroll
    for (int mf = 0; mf < 8; ++mf) {
#pragma unroll
        for (int j = 0; j < 4; ++j) {
            int rr = row0 + wm * 128 + mf * 16 + lh * 4 + j;
            int pt2 = pair_tok2[rr];
            float wt = pair_w[rr];
            if (pt2 >= 0) {
                float* op = ob + (size_t)pt2 * HD + by * 256 + wn * 64 + l15;
#pragma unroll
                for (int nf = 0; nf < 4; ++nf) {
                    op[nf * 16] = acc[mf][nf][j] * wt;
                }
            }
        }
    }
}

// ---------------- combine: out[t] = ob[2t] + ob[2t+1] ----------------
__global__ __launch_bounds__(256) void combine_kernel(const float* __restrict__ ob,
                                                      float* __restrict__ out) {
    int t = blockIdx.x;
    const f32x4* r0 = (const f32x4*)(ob + (size_t)(2 * t) * HD);
    const f32x4* r1 = (const f32x4*)(ob + (size_t)(2 * t + 1) * HD);
    f32x4* o = (f32x4*)(out + (size_t)t * HD);
#pragma unroll
    for (int i = 0; i < 2; ++i) {
        int idx = threadIdx.x + i * 256;
        o[idx] = r0[idx] + r1[idx];
    }
}

extern "C" void kernel_launch(void* const* d_in, const int* in_sizes, int n_in,
                              void* d_out, int out_size, void* d_ws, size_t ws_size,
                              hipStream_t stream) {
    (void)in_sizes; (void)n_in; (void)ws_size; (void)out_size;
    const float* x  = (const float*)d_in[0];
    const float* wg = (const float*)d_in[1];
    const float* w1 = (const float*)d_in[2];
    const float* w3 = (const float*)d_in[3];
    const float* w2 = (const float*)d_in[4];
    float* out = (float*)d_out;

    char* ws = (char*)d_ws;
    size_t off = 0;
    auto alloc = [&](size_t bytes) -> void* {
        void* p = ws + off;
        off = (off + bytes + 255) & ~(size_t)255;
        return p;
    };
    u16* xh          = (u16*)alloc((size_t)TOK * HD * 2);
    u16* hb          = (u16*)alloc((size_t)PPAD * ID * 2);
    u16* wcat        = (u16*)alloc((size_t)NE * 2 * ID * HD * 2);  // w13 fp16 (gemm1 phase)
    // after gemm1: first half of wcat becomes ob [2*TOK][HD] fp32 (exact fit);
    // second half becomes w2t [E][H][I] fp16.
    float* ob        = (float*)wcat;
    u16* w2t         = wcat + (size_t)NE * ID * HD;
    int* pair_tok2   = (int*)alloc((size_t)PPAD * 4);
    float* pair_w    = (float*)alloc((size_t)PPAD * 4);
    int* top_e       = (int*)alloc((size_t)TOK * 2 * 4);
    float* top_w     = (float*)alloc((size_t)TOK * 2 * 4);
    int* counts      = (int*)alloc(64);
    int* offs        = (int*)alloc(64);
    int* mt_e        = (int*)alloc((size_t)MAXMT * 4);
    int* mt_r0       = (int*)alloc((size_t)MAXMT * 4);
    int* nmt         = (int*)alloc(64);

    hipMemsetAsync(counts, 0, 64, stream);

    cast_x_kernel<<<TOK * HD / 8 / 256, 256, 0, stream>>>(x, xh);
    router_kernel<<<TOK / 4, 256, 0, stream>>>(x, wg, top_e, top_w, counts);
    offsets_kernel<<<1, 64, 0, stream>>>(counts, offs, mt_e, mt_r0, nmt);
    scatter_kernel<<<NE, 256, 0, stream>>>(top_e, top_w, counts, offs, pair_tok2, pair_w);
    prep_w13_kernel<<<dim3(HD / 64, ID / 64, NE * 2), 256, 0, stream>>>(w1, w3, wcat);
    // gemm1: 72 mt x 32 by, XCD-clustered 1D launch (4mt x 8by clusters)
    gemm1_kernel<<<2304, 512, 0, stream>>>(xh, wcat, pair_tok2, mt_e, mt_r0, nmt, hb);
    prep_w2_kernel<<<dim3(ID / 64, HD / 64, NE), 256, 0, stream>>>(w2, w2t);  // into wcat 2nd half
    // gemm2: mt padded to 96 x 8 by, XCD-clustered (4mt x 8by clusters)
    gemm2_kernel<<<768, 512, 0, stream>>>(hb, w2t, pair_tok2, pair_w, mt_e, mt_r0, nmt, ob);
    combine_kernel<<<TOK, 256, 0, stream>>>(ob, out);
}

// Round 7
// 1396.168 us; speedup vs baseline: 1.0065x; 1.0065x over previous
//
#include <hip/hip_runtime.h>
#include <hip/hip_bf16.h>
#include <hip/hip_fp16.h>

// ---- problem constants ----
#define TOK 8192      // 4*2048 tokens
#define HD 2048       // hidden
#define ID 4096       // intermediate
#define NE 8          // experts
#define NPAIR (TOK*2) // token-expert pairs (TOPK=2)
#define BM 256
#define MAXMT (NPAIR/BM + NE)   // 72 worst-case M-tiles
#define PPAD (NPAIR + NE*BM)    // 18432 worst-case padded rows

typedef unsigned short u16;
typedef unsigned int u32;
typedef __attribute__((ext_vector_type(4))) float f32x4;
typedef __attribute__((ext_vector_type(4))) int   i32x4;
typedef u16 u16x8 __attribute__((ext_vector_type(8)));
typedef u16 u16x4 __attribute__((ext_vector_type(4)));

__device__ __forceinline__ u16 f2h(float f) {
    __half h = __float2half_rn(f);
    return *reinterpret_cast<u16*>(&h);
}

// ---------------- cast x fp32 -> fp16 ----------------
__global__ void cast_x_kernel(const float* __restrict__ x, u16* __restrict__ xh) {
    size_t idx = (size_t)blockIdx.x * 256 + threadIdx.x;   // 8 elems each
    const f32x4* p = (const f32x4*)x + idx * 2;
    f32x4 a = p[0], b = p[1];
    u16x8 o;
#pragma unroll
    for (int i = 0; i < 4; ++i) { o[i] = f2h(a[i]); o[4 + i] = f2h(b[i]); }
    *((u16x8*)xh + idx) = o;
}

// ---------------- prep: w1/w3 fp32 [H][I] -> interleaved fp16 wcat [2*I][H] ----------------
__global__ __launch_bounds__(256) void prep_w13_kernel(const float* __restrict__ w1,
                                                       const float* __restrict__ w3,
                                                       u16* __restrict__ wcat) {
    __shared__ u16 tile[64][68];   // [n_local][k_local]
    const int k0 = blockIdx.x * 64, n0 = blockIdx.y * 64;
    const int e = blockIdx.z >> 1, which = blockIdx.z & 1;
    const float* src = (which ? w3 : w1) + (size_t)e * HD * ID;
    u16* dst = wcat + (size_t)e * 2 * ID * HD;
    const int tid = threadIdx.x, r = tid >> 4, c4 = (tid & 15) * 4;
#pragma unroll
    for (int i = 0; i < 4; ++i) {
        int k = k0 + r + 16 * i;
        f32x4 v = *(const f32x4*)(src + (size_t)k * ID + n0 + c4);
#pragma unroll
        for (int j = 0; j < 4; ++j) tile[c4 + j][r + 16 * i] = f2h(v[j]);
    }
    __syncthreads();
#pragma unroll
    for (int i = 0; i < 4; ++i) {
        int nl = r + 16 * i;
        int n = n0 + nl;
        int wr = ((n >> 4) << 5) | (which << 4) | (n & 15);
        u16x4 o;
#pragma unroll
        for (int j = 0; j < 4; ++j) o[j] = tile[nl][c4 + j];
        *(u16x4*)(dst + (size_t)wr * HD + k0 + c4) = o;
    }
}

// ---------------- prep: w2 fp32 [I][H] -> fp16 w2t [H][I] ----------------
__global__ __launch_bounds__(256) void prep_w2_kernel(const float* __restrict__ w2,
                                                      u16* __restrict__ w2t) {
    __shared__ u16 tile[64][68];
    const int k0 = blockIdx.x * 64, n0 = blockIdx.y * 64;
    const int e = blockIdx.z;
    const float* src = w2 + (size_t)e * ID * HD;
    u16* dst = w2t + (size_t)e * ID * HD;
    const int tid = threadIdx.x, r = tid >> 4, c4 = (tid & 15) * 4;
#pragma unroll
    for (int i = 0; i < 4; ++i) {
        int k = k0 + r + 16 * i;
        f32x4 v = *(const f32x4*)(src + (size_t)k * HD + n0 + c4);
#pragma unroll
        for (int j = 0; j < 4; ++j) tile[c4 + j][r + 16 * i] = f2h(v[j]);
    }
    __syncthreads();
#pragma unroll
    for (int i = 0; i < 4; ++i) {
        int nl = r + 16 * i;
        u16x4 o;
#pragma unroll
        for (int j = 0; j < 4; ++j) o[j] = tile[nl][c4 + j];
        *(u16x4*)(dst + (size_t)(n0 + nl) * ID + k0 + c4) = o;
    }
}

// ---------------- router: fp32 logits, softcap, softmax, top2 ----------------
__global__ void router_kernel(const float* __restrict__ x, const float* __restrict__ wg,
                              int* __restrict__ top_e, float* __restrict__ top_w,
                              int* __restrict__ counts) {
    int t = blockIdx.x * 4 + (threadIdx.x >> 6);
    int l = threadIdx.x & 63;
    const float* xr = x + (size_t)t * HD;
    float acc[NE];
#pragma unroll
    for (int e = 0; e < NE; ++e) acc[e] = 0.f;
    for (int h0 = 0; h0 < HD; h0 += 64) {
        int h = h0 + l;
        float xv = xr[h];
        const f32x4* wr = (const f32x4*)(wg + (size_t)h * NE);
        f32x4 w0 = wr[0], w1v = wr[1];
#pragma unroll
        for (int i = 0; i < 4; ++i) { acc[i] += xv * w0[i]; acc[4 + i] += xv * w1v[i]; }
    }
#pragma unroll
    for (int e = 0; e < NE; ++e) {
        float v = acc[e];
        for (int s = 32; s >= 1; s >>= 1) v += __shfl_xor(v, s);
        acc[e] = v;
    }
    if (l == 0) {
        float li[NE], mx = -1e30f;
#pragma unroll
        for (int e = 0; e < NE; ++e) { li[e] = 30.f * tanhf(acc[e] * (1.f / 30.f)); mx = fmaxf(mx, li[e]); }
        float p[NE], se = 0.f;
#pragma unroll
        for (int e = 0; e < NE; ++e) { p[e] = expf(li[e] - mx); se += p[e]; }
        float inv = 1.f / se;
        int i1 = 0; float p1 = p[0];
#pragma unroll
        for (int e = 1; e < NE; ++e) if (p[e] > p1) { p1 = p[e]; i1 = e; }
        int i2 = -1; float p2 = -1e30f;
#pragma unroll
        for (int e = 0; e < NE; ++e) if (e != i1 && p[e] > p2) { p2 = p[e]; i2 = e; }
        top_e[t * 2] = i1; top_e[t * 2 + 1] = i2;
        top_w[t * 2] = p1 * inv; top_w[t * 2 + 1] = p2 * inv;
        atomicAdd(&counts[i1], 1); atomicAdd(&counts[i2], 1);
    }
}

// ---------------- offsets + M-tile table (1 thread), 256-row tiles ----------------
__global__ void offsets_kernel(const int* __restrict__ counts, int* __restrict__ offs,
                               int* __restrict__ mt_e, int* __restrict__ mt_r0,
                               int* __restrict__ nmt) {
    if (threadIdx.x != 0) return;
    int off = 0, n = 0;
    for (int e = 0; e < NE; ++e) {
        offs[e] = off;
        int c = counts[e];
        int nt = (c + 255) >> 8;
        for (int j = 0; j < nt; ++j) { mt_e[n] = e; mt_r0[n] = off + j * 256; ++n; }
        off += nt * 256;
    }
    offs[NE] = off;
    *nmt = n;
}

// ---------------- deterministic per-expert compaction ----------------
// pair_tok2[pos] = token*2 + slot; pads = -2
__global__ void scatter_kernel(const int* __restrict__ top_e, const float* __restrict__ top_w,
                               const int* __restrict__ counts, const int* __restrict__ offs,
                               int* __restrict__ pair_tok2, float* __restrict__ pair_w) {
    const int e = blockIdx.x;
    const int tid = threadIdx.x;
    __shared__ int sc[256];
    int base = offs[e];
    for (int start = 0; start < TOK; start += 256) {
        int tk = start + tid;
        int m = 0; float w = 0.f; int slot = 0;
        int e0 = top_e[tk * 2], e1 = top_e[tk * 2 + 1];
        if (e0 == e) { m = 1; w = top_w[tk * 2]; slot = 0; }
        else if (e1 == e) { m = 1; w = top_w[tk * 2 + 1]; slot = 1; }
        sc[tid] = m;
        __syncthreads();
        for (int s = 1; s < 256; s <<= 1) {
            int v = (tid >= s) ? sc[tid - s] : 0;
            __syncthreads();
            sc[tid] += v;
            __syncthreads();
        }
        if (m) { int pos = base + sc[tid] - 1; pair_tok2[pos] = tk * 2 + slot; pair_w[pos] = w; }
        base += sc[255];
        __syncthreads();
    }
    int cnt = counts[e];
    int padded = (cnt + 255) & ~255;
    for (int r = cnt + tid; r < padded; r += 256) {
        pair_tok2[offs[e] + r] = -2;
        pair_w[offs[e] + r] = 0.f;
    }
}

// ======================= 8-phase 256x256 GEMM machinery =======================
// LDS byte bases: A0=0, A1=32768, A2=65536 (triple-buffered A), B0=98304, B1=131072
#define A0B 0u
#define A1B 32768u
#define A2B 65536u
#define B0B 98304u
#define B1B 131072u

// stage one half-tile (128 rows x 64 cols fp16) = 2 global_load_lds x 512 thr x 16B
#define STAGE(GB, OFF, LB, H) do { \
    _Pragma("unroll") \
    for (int cc_ = 0; cc_ < 2; ++cc_) { \
        __builtin_amdgcn_global_load_lds( \
            (const __attribute__((address_space(1))) void*)((GB) + OFF[(H) * 2 + cc_]), \
            (__attribute__((address_space(3))) void*)((char*)lds + (LB) + (H) * 16384 + cc_ * 8192 + wv * 1024), \
            16, 0, 0); \
        OFF[(H) * 2 + cc_] += 128; \
    } \
} while (0)

#define LOAD_B(BUFB) do { \
    _Pragma("unroll") \
    for (int nf_ = 0; nf_ < 4; ++nf_) { \
        _Pragma("unroll") \
        for (int kk_ = 0; kk_ < 2; ++kk_) { \
            int nn_ = wn * 64 + nf_ * 16 + l15; \
            int lb_ = (lh * 16 + kk_ * 64) ^ ((nn_ & 7) << 4); \
            bb[nf_][kk_] = *(const i32x4*)((const char*)lds + (BUFB) + nn_ * 128 + lb_); \
        } } \
} while (0)

// phase: {4x ds_read a-frags | stage issue | barrier | lgkm0+schedbar | prio1 | 16 MFMA | prio0 | tail | barrier}
#define DO_PHASE(Q, ABUF, STAGE_STMT, TAIL_STMT) do { \
    i32x4 aa_[2][2]; \
    _Pragma("unroll") \
    for (int m2_ = 0; m2_ < 2; ++m2_) { \
        _Pragma("unroll") \
        for (int kk_ = 0; kk_ < 2; ++kk_) { \
            int rr_ = wm * 128 + ((Q) * 2 + m2_) * 16 + l15; \
            int lb_ = (lh * 16 + kk_ * 64) ^ ((rr_ & 7) << 4); \
            aa_[m2_][kk_] = *(const i32x4*)((const char*)lds + (ABUF) + rr_ * 128 + lb_); \
        } } \
    STAGE_STMT; \
    __builtin_amdgcn_s_barrier(); \
    asm volatile("s_waitcnt lgkmcnt(0)" ::: "memory"); \
    __builtin_amdgcn_sched_barrier(0); \
    __builtin_amdgcn_s_setprio(1); \
    _Pragma("unroll") \
    for (int m2_ = 0; m2_ < 2; ++m2_) { \
        _Pragma("unroll") \
        for (int nf_ = 0; nf_ < 4; ++nf_) { \
            _Pragma("unroll") \
            for (int kk_ = 0; kk_ < 2; ++kk_) { \
                asm("v_mfma_f32_16x16x32_f16 %0, %1, %2, %0" \
                    : "+v"(acc[(Q) * 2 + m2_][nf_]) \
                    : "v"(aa_[m2_][kk_]), "v"(bb[nf_][kk_])); \
            } } } \
    __builtin_amdgcn_s_setprio(0); \
    TAIL_STMT; \
    __builtin_amdgcn_s_barrier(); \
} while (0)

#define VM8  asm volatile("s_waitcnt vmcnt(8)"  ::: "memory")
#define VM0  asm volatile("s_waitcnt vmcnt(0)"  ::: "memory")

// one K-tile group.
// A(g+2) -> aN2 at ph0-1: aN2 holds dead A(g-1); all its reads retired before
//   the group-entry barrier (each wave's ph3 lgkmcnt(0) precedes that barrier).
// B(g+2) -> bCur at ph2-3: LOAD_B(bCur) reads retired at ph0's lgkmcnt(0),
//   published to all waves by the ph0/ph1 end barriers. (R6 bug: staged at ph0,
//   racing the still-queued LOAD_B ds_reads.)
#define GROUP(SA, SB, TAIL) do { \
    LOAD_B(bCur); \
    DO_PHASE(0, aCur, if (SA) STAGE(abase, aoff, aN2, 0), (void)0); \
    DO_PHASE(1, aCur, if (SA) STAGE(abase, aoff, aN2, 1), (void)0); \
    DO_PHASE(2, aCur, if (SB) STAGE(bbase, boff, bCur, 0), (void)0); \
    DO_PHASE(3, aCur, if (SB) STAGE(bbase, boff, bCur, 1), TAIL); \
    u32 t_ = aCur; aCur = aNxt; aNxt = aN2; aN2 = t_; \
    t_ = bCur; bCur = bNxt; bNxt = t_; \
} while (0)

// ---------------- GEMM1: h = silu(x@w1)*(x@w3), 256x256 8-phase fp16 MFMA ----------------
__global__ __launch_bounds__(512, 1) void gemm1_kernel(
    const u16* __restrict__ xh, const u16* __restrict__ wcat,
    const int* __restrict__ pair_tok2, const int* __restrict__ mt_e,
    const int* __restrict__ mt_r0, const int* __restrict__ nmt,
    u16* __restrict__ hb) {
    // XCD-pure 32-block clusters (4mt x 8by); grid 2304 = 72 clusters
    int p = blockIdx.x;
    int xc = p & 7, jj_ = p >> 3, cl = jj_ >> 5, sl = jj_ & 31;
    int C = cl * 8 + xc;
    int mt = (C % 18) * 4 + (sl >> 3);
    int by = (C / 18) * 8 + (sl & 7);
    if (mt >= *nmt) return;
    const int e = mt_e[mt], row0 = mt_r0[mt];
    const int tid = threadIdx.x, lane = tid & 63, wv = tid >> 6;
    const int wm = wv >> 2, wn = wv & 3;
    const int l15 = lane & 15, lh = lane >> 4;

    __shared__ u16 lds[81920];   // 160 KB: A0,A1,A2,B0,B1

    u32 aoff[4], boff[4];
    const char* abase = (const char*)xh;
    const char* bbase = (const char*)(wcat + (size_t)e * 2 * ID * HD);
    {
        int rl_ = tid >> 3, ch_ = tid & 7;
#pragma unroll
        for (int h = 0; h < 2; ++h)
#pragma unroll
            for (int cc = 0; cc < 2; ++cc) {
                int r = h * 128 + cc * 64 + rl_;
                int kbs = (ch_ * 16) ^ ((r & 7) << 4);
                int pt2 = pair_tok2[row0 + r];
                int tok = pt2 < 0 ? 0 : (pt2 >> 1);
                aoff[h * 2 + cc] = (u32)(tok * (HD * 2)) + kbs;
                boff[h * 2 + cc] = (u32)((by * 256 + r) * (HD * 2)) + kbs;
            }
    }

    f32x4 acc[8][4];
#pragma unroll
    for (int i0 = 0; i0 < 8; ++i0)
#pragma unroll
        for (int i1 = 0; i1 < 4; ++i1) acc[i0][i1] = (f32x4)0.f;
    i32x4 bb[4][2];
    u32 aCur = A0B, aNxt = A1B, aN2 = A2B, bCur = B0B, bNxt = B1B;

    // prologue: A(0),B(0),A(1),B(1) = 16 loads; VM8 retires A0,B0; A1,B1 in flight
    STAGE(abase, aoff, A0B, 0); STAGE(abase, aoff, A0B, 1);
    STAGE(bbase, boff, B0B, 0); STAGE(bbase, boff, B0B, 1);
    STAGE(abase, aoff, A1B, 0); STAGE(abase, aoff, A1B, 1);
    STAGE(bbase, boff, B1B, 0); STAGE(bbase, boff, B1B, 1);
    VM8;
    __builtin_amdgcn_s_barrier();

    const int NT = HD / 64;   // 32
#pragma unroll 1
    for (int g = 0; g <= NT - 3; ++g) GROUP(true, true, VM8);
    GROUP(false, false, VM0);                      // g = NT-2
    GROUP(false, false, (void)0);                  // g = NT-1

    // epilogue: nf even = gate, nf odd = up; real col = by*128 + wn*32 + np*16 + l15
#pragma unroll
    for (int mf = 0; mf < 8; ++mf) {
#pragma unroll
        for (int j = 0; j < 4; ++j) {
            size_t rr = (size_t)row0 + wm * 128 + mf * 16 + lh * 4 + j;
            u16* hp_ = hb + rr * ID + by * 128 + wn * 32 + l15;
#pragma unroll
            for (int np = 0; np < 2; ++np) {
                float g = acc[mf][2 * np][j], u = acc[mf][2 * np + 1][j];
                float s = g / (1.f + expf(-g));
                hp_[np * 16] = f2h(s * u);
            }
        }
    }
}

// ---------------- GEMM2: ob[tok*2+slot] = (h@w2t)*weight, 256x256 8-phase ----------------
__global__ __launch_bounds__(512, 1) void gemm2_kernel(
    const u16* __restrict__ hb, const u16* __restrict__ w2t,
    const int* __restrict__ pair_tok2, const float* __restrict__ pair_w,
    const int* __restrict__ mt_e, const int* __restrict__ mt_r0, const int* __restrict__ nmt,
    float* __restrict__ ob) {
    // XCD-pure 32-block clusters (4mt x 8by); grid 768 = 24 clusters, mt padded to 96
    int p = blockIdx.x;
    int xc = p & 7, jj_ = p >> 3, cl = jj_ >> 5, sl = jj_ & 31;
    int C = cl * 8 + xc;
    int mt = C * 4 + (sl >> 3);
    int by = sl & 7;
    if (mt >= *nmt) return;
    const int e = mt_e[mt], row0 = mt_r0[mt];
    const int tid = threadIdx.x, lane = tid & 63, wv = tid >> 6;
    const int wm = wv >> 2, wn = wv & 3;
    const int l15 = lane & 15, lh = lane >> 4;

    __shared__ u16 lds[81920];

    u32 aoff[4], boff[4];
    const char* abase = (const char*)hb;
    const char* bbase = (const char*)(w2t + (size_t)e * HD * ID);
    {
        int rl_ = tid >> 3, ch_ = tid & 7;
#pragma unroll
        for (int h = 0; h < 2; ++h)
#pragma unroll
            for (int cc = 0; cc < 2; ++cc) {
                int r = h * 128 + cc * 64 + rl_;
                int kbs = (ch_ * 16) ^ ((r & 7) << 4);
                aoff[h * 2 + cc] = (u32)((row0 + r) * (ID * 2)) + kbs;
                boff[h * 2 + cc] = (u32)((by * 256 + r) * (ID * 2)) + kbs;
            }
    }

    f32x4 acc[8][4];
#pragma unroll
    for (int i0 = 0; i0 < 8; ++i0)
#pragma unroll
        for (int i1 = 0; i1 < 4; ++i1) acc[i0][i1] = (f32x4)0.f;
    i32x4 bb[4][2];
    u32 aCur = A0B, aNxt = A1B, aN2 = A2B, bCur = B0B, bNxt = B1B;

    STAGE(abase, aoff, A0B, 0); STAGE(abase, aoff, A0B, 1);
    STAGE(bbase, boff, B0B, 0); STAGE(bbase, boff, B0B, 1);
    STAGE(abase, aoff, A1B, 0); STAGE(abase, aoff, A1B, 1);
    STAGE(bbase, boff, B1B, 0); STAGE(bbase, boff, B1B, 1);
    VM8;
    __builtin_amdgcn_s_barrier();

    const int NT = ID / 64;   // 64
#pragma unroll 1
    for (int g = 0; g <= NT - 3; ++g) GROUP(true, true, VM8);
    GROUP(false, false, VM0);
    GROUP(false, false, (void)0);

#pragma unroll
    for (int mf = 0; mf < 8; ++mf) {
#pragma unroll
        for (int j = 0; j < 4; ++j) {
            int rr = row0 + wm * 128 + mf * 16 + lh * 4 + j;
            int pt2 = pair_tok2[rr];
            float wt = pair_w[rr];
            if (pt2 >= 0) {
                float* op = ob + (size_t)pt2 * HD + by * 256 + wn * 64 + l15;
#pragma unroll
                for (int nf = 0; nf < 4; ++nf) {
                    op[nf * 16] = acc[mf][nf][j] * wt;
                }
            }
        }
    }
}

// ---------------- combine: out[t] = ob[2t] + ob[2t+1] ----------------
__global__ __launch_bounds__(256) void combine_kernel(const float* __restrict__ ob,
                                                      float* __restrict__ out) {
    int t = blockIdx.x;
    const f32x4* r0 = (const f32x4*)(ob + (size_t)(2 * t) * HD);
    const f32x4* r1 = (const f32x4*)(ob + (size_t)(2 * t + 1) * HD);
    f32x4* o = (f32x4*)(out + (size_t)t * HD);
#pragma unroll
    for (int i = 0; i < 2; ++i) {
        int idx = threadIdx.x + i * 256;
        o[idx] = r0[idx] + r1[idx];
    }
}

extern "C" void kernel_launch(void* const* d_in, const int* in_sizes, int n_in,
                              void* d_out, int out_size, void* d_ws, size_t ws_size,
                              hipStream_t stream) {
    (void)in_sizes; (void)n_in; (void)ws_size; (void)out_size;
    const float* x  = (const float*)d_in[0];
    const float* wg = (const float*)d_in[1];
    const float* w1 = (const float*)d_in[2];
    const float* w3 = (const float*)d_in[3];
    const float* w2 = (const float*)d_in[4];
    float* out = (float*)d_out;

    char* ws = (char*)d_ws;
    size_t off = 0;
    auto alloc = [&](size_t bytes) -> void* {
        void* p = ws + off;
        off = (off + bytes + 255) & ~(size_t)255;
        return p;
    };
    u16* xh          = (u16*)alloc((size_t)TOK * HD * 2);
    u16* hb          = (u16*)alloc((size_t)PPAD * ID * 2);
    u16* wcat        = (u16*)alloc((size_t)NE * 2 * ID * HD * 2);  // w13 fp16 (gemm1 phase)
    // after gemm1: first half of wcat becomes ob [2*TOK][HD] fp32 (exact fit);
    // second half becomes w2t [E][H][I] fp16.
    float* ob        = (float*)wcat;
    u16* w2t         = wcat + (size_t)NE * ID * HD;
    int* pair_tok2   = (int*)alloc((size_t)PPAD * 4);
    float* pair_w    = (float*)alloc((size_t)PPAD * 4);
    int* top_e       = (int*)alloc((size_t)TOK * 2 * 4);
    float* top_w     = (float*)alloc((size_t)TOK * 2 * 4);
    int* counts      = (int*)alloc(64);
    int* offs        = (int*)alloc(64);
    int* mt_e        = (int*)alloc((size_t)MAXMT * 4);
    int* mt_r0       = (int*)alloc((size_t)MAXMT * 4);
    int* nmt         = (int*)alloc(64);

    hipMemsetAsync(counts, 0, 64, stream);

    cast_x_kernel<<<TOK * HD / 8 / 256, 256, 0, stream>>>(x, xh);
    router_kernel<<<TOK / 4, 256, 0, stream>>>(x, wg, top_e, top_w, counts);
    offsets_kernel<<<1, 64, 0, stream>>>(counts, offs, mt_e, mt_r0, nmt);
    scatter_kernel<<<NE, 256, 0, stream>>>(top_e, top_w, counts, offs, pair_tok2, pair_w);
    prep_w13_kernel<<<dim3(HD / 64, ID / 64, NE * 2), 256, 0, stream>>>(w1, w3, wcat);
    // gemm1: 72 mt x 32 by, XCD-clustered 1D launch (4mt x 8by clusters)
    gemm1_kernel<<<2304, 512, 0, stream>>>(xh, wcat, pair_tok2, mt_e, mt_r0, nmt, hb);
    prep_w2_kernel<<<dim3(ID / 64, HD / 64, NE), 256, 0, stream>>>(w2, w2t);  // into wcat 2nd half
    // gemm2: mt padded to 96 x 8 by, XCD-clustered (4mt x 8by clusters)
    gemm2_kernel<<<768, 512, 0, stream>>>(hb, w2t, pair_tok2, pair_w, mt_e, mt_r0, nmt, ob);
    combine_kernel<<<TOK, 256, 0, stream>>>(ob, out);
}